// Round 6
// baseline (33.550 us; speedup 1.0000x reference)
//
#include <hip/hip_runtime.h>
#include <math.h>

// Problem constants (match reference setup_inputs)
#define BS 32
#define NA 3
#define NC 80
#define HH 52
#define WW 52
#define TPER 50                 // targets per batch image
#define NTT (BS * TPER)         // 1600 total targets
#define HW (HH * WW)            // 2704
#define CPB (NA * HW)           // 8112 cells per batch image
#define CH (5 + NC)             // 85 channels per anchor
#define CELLS_PER_BLK 512       // 256 threads x 2 cells each
#define CBPB 16                 // cell-blocks per batch: 16*512 = 8192 >= 8112
#define NBLK (BS * CBPB)        // 512 blocks total

__device__ __forceinline__ float sigm(float v) { return 1.0f / (1.0f + expf(-v)); }

// ws layout: float2 ws[NBLK] = {pre-weighted loss partial, n_valid contribution}
// (only yb==0 blocks report n_valid of their batch; total = sum)

__global__ __launch_bounds__(256) void k_main(const float* __restrict__ in,
                                              const float* __restrict__ tgt,
                                              float2* __restrict__ ws)
{
    __shared__ float4 sbox[TPER];                 // {x1, x2, y1, y2}
    __shared__ int   scell[TPER], scls[TPER];
    __shared__ float stx[TPER], sty[TPER], stw[TPER], sth[TPER];
    __shared__ unsigned smask[TPER][3];           // multi-hot class union (owners)
    __shared__ unsigned char sown[TPER];
    __shared__ unsigned sbm[CELLS_PER_BLK / 32];  // target-cell bitmap for this range
    __shared__ int slist[TPER];                   // owned targets in this range
    __shared__ int scnt;
    __shared__ float snv;
    __shared__ float red[256];

    const int tid = threadIdx.x;
    const int b  = blockIdx.x >> 4;               // / CBPB
    const int yb = blockIdx.x & (CBPB - 1);
    const int lo = yb * CELLS_PER_BLK;
    const float aw[3] = {1.25f, 2.0f, 4.125f};
    const float ah[3] = {1.625f, 3.75f, 2.875f};

    // ---- phase 0+1: zero shared & per-target prep (tid<50) ----
    if (tid == 0) { scnt = 0; snv = 0.0f; }
    if (tid < CELLS_PER_BLK / 32) sbm[tid] = 0u;
    if (tid < TPER) {
        const float* p = tgt + (size_t)(b * TPER + tid) * 5;
        float c0 = p[0], c1 = p[1], c2 = p[2], c3 = p[3], c4 = p[4];
        bool valid = (c0 + c1 + c2 + c3 + c4) > 0.0f;
        float gx = c1 * WW, gy = c2 * HH, gw = c3 * WW, gh = c4 * HH;
        int gi = (int)gx; gi = gi < 0 ? 0 : (gi > WW - 1 ? WW - 1 : gi);
        int gj = (int)gy; gj = gj < 0 ? 0 : (gj > HH - 1 ? HH - 1 : gj);
        int bn = 0; float best = -1.0f;
        for (int a = 0; a < 3; ++a) {
            float inter = fminf(gw, aw[a]) * fminf(gh, ah[a]);
            float uni = gw * gh + aw[a] * ah[a] - inter;
            float iou = inter / (uni + 1e-16f);
            if (iou > best) { best = iou; bn = a; }   // strict >: argmax keeps first
        }
        scell[tid] = valid ? (bn * HW + gj * WW + gi) : -1;
        int cls = (int)c0; cls = cls < 0 ? 0 : (cls > NC - 1 ? NC - 1 : cls);
        scls[tid] = cls;
        sbox[tid] = valid ? make_float4(gx - 0.5f * gw, gx + 0.5f * gw,
                                        gy - 0.5f * gh, gy + 0.5f * gh)
                          : make_float4(1e30f, 1e30f, 1e30f, 1e30f);
        stx[tid] = gx - (float)gi;
        sty[tid] = gy - (float)gj;
        stw[tid] = logf(gw / aw[bn] + 1e-16f);
        sth[tid] = logf(gh / ah[bn] + 1e-16f);
        unsigned long long vm = __ballot(valid);      // lanes 0..49 of wave 0
        if (tid == 0) snv = (float)__popcll(vm);
    }
    __syncthreads();

    // ---- phase 2: ownership, class-union masks, bitmap, owned-target list ----
    if (tid < TPER) {
        int c = scell[tid];
        bool own = (c >= 0);
        if (own) {
            for (int t2 = tid + 1; t2 < TPER; ++t2)
                if (scell[t2] == c) { own = false; break; }   // later valid writer wins
        }
        sown[tid] = own;
        if (own) {
            unsigned m0 = 0, m1 = 0, m2 = 0;                  // multi-hot on collision
            for (int t2 = 0; t2 < TPER; ++t2)
                if (scell[t2] == c) {
                    int cc = scls[t2];
                    if (cc < 32) m0 |= 1u << cc;
                    else if (cc < 64) m1 |= 1u << (cc - 32);
                    else m2 |= 1u << (cc - 64);
                }
            smask[tid][0] = m0; smask[tid][1] = m1; smask[tid][2] = m2;
            if (c >= lo && c < lo + CELLS_PER_BLK) {
                int p = atomicAdd(&scnt, 1);
                slist[p] = tid;
            }
        }
        if (c >= lo && c < lo + CELLS_PER_BLK)
            atomicOr(&sbm[(c - lo) >> 5], 1u << ((c - lo) & 31));
    }
    __syncthreads();

    // ---- phase 3: dense cells (noobj BCE + a_loss), 2 cells/thread ----
    float term = 0.0f;
    float P1[2], P2[2], Q1[2], Q2[2], A2[2], CF[2];
    bool ACT[2], IGN[2] = {false, false};
    #pragma unroll
    for (int k = 0; k < 2; ++k) {
        int idx = lo + tid + k * 256;
        ACT[k] = idx < CPB;
        P1[k] = 0.0f; P2[k] = 0.0f; Q1[k] = 0.0f; Q2[k] = 0.0f;
        A2[k] = 1e30f; CF[k] = 0.5f;
        if (ACT[k]) {
            int a = idx / HW;
            int r = idx - a * HW;
            int yy = r / WW;
            int xx = r - yy * WW;
            const float* base = in + ((size_t)b * (NA * CH) + a * CH) * HW + r;
            float xr = base[0], yr = base[HW], wr = base[2 * HW],
                  hr = base[3 * HW], cr = base[4 * HW];
            float sx = sigm(xr), sy = sigm(yr);
            CF[k] = sigm(cr);
            float px = sx + (float)xx, py = sy + (float)yy;
            float pw = expf(wr) * aw[a], ph = expf(hr) * ah[a];
            P1[k] = px - 0.5f * pw; P2[k] = px + 0.5f * pw;
            Q1[k] = py - 0.5f * ph; Q2[k] = py + 0.5f * ph;
            A2[k] = pw * ph + 1e-16f;
            term += 0.05f * ((sx - 0.5f) * (sx - 0.5f) + (sy - 0.5f) * (sy - 0.5f)
                             + wr * wr + hr * hr);            // 0.1/2 pre-weight
        }
    }
    for (int t = 0; t < TPER; ++t) {
        float4 bx = sbox[t];                                  // one ds_read_b128 / target
        float ar = (bx.y - bx.x) * (bx.w - bx.z);             // area1 (0 for sentinel)
        #pragma unroll
        for (int k = 0; k < 2; ++k) {
            float iw = fmaxf(fminf(bx.y, P2[k]) - fmaxf(bx.x, P1[k]), 0.0f);
            float ih = fmaxf(fminf(bx.w, Q2[k]) - fmaxf(bx.z, Q1[k]), 0.0f);
            float inter = iw * ih;
            // iou >= 0.5  <=>  3*inter >= area1 + area2 + eps (denominator > 0)
            IGN[k] = IGN[k] || (3.0f * inter >= ar + A2[k]);
        }
    }
    #pragma unroll
    for (int k = 0; k < 2; ++k) {
        int d = tid + k * 256;
        bool ist = (sbm[d >> 5] >> (d & 31)) & 1u;
        if (ACT[k] && !IGN[k] && !ist)
            term += -logf(fmaxf(1.0f - CF[k], 1e-12f));       // noobj pre-weight 5*0.2=1
    }

    // ---- phase 4: owned-target tail (3 targets concurrently, 85 threads each) ----
    const int nlist = scnt;
    const int g = tid / 85;                                   // 0..2 (tid 255 idle)
    const int k = tid - g * 85;
    for (int base_i = 0; base_i < nlist; base_i += 3) {
        int li = base_i + g;
        if (g < 3 && li < nlist) {
            int t = slist[li];
            int cell = scell[t];
            int a = cell / HW;
            int r = cell - a * HW;
            const float* bp = in + ((size_t)b * (NA * CH) + a * CH) * HW + r;
            float t2m;
            if (k < 5) {                                      // x,y,w,h,conf
                float v = bp[(size_t)k * HW];
                if (k == 0)      { float d = sigm(v) - stx[t]; t2m = 0.5f * d * d; }
                else if (k == 1) { float d = sigm(v) - sty[t]; t2m = 0.5f * d * d; }
                else if (k == 2) { float d = v - stw[t];       t2m = 0.5f * d * d; }
                else if (k == 3) { float d = v - sth[t];       t2m = 0.5f * d * d; }
                else             { t2m = -5.0f * logf(fmaxf(sigm(v), 1e-12f)); }
            } else {                                          // class c = k-5
                int c = k - 5;
                float p = sigm(bp[(size_t)(5 + c) * HW]);
                bool pos = (smask[t][c >> 5] >> (c & 31)) & 1u;
                t2m = pos ? -logf(fmaxf(p, 1e-12f)) : -logf(fmaxf(1.0f - p, 1e-12f));
            }
            term += t2m;                                      // folds into block tree
        }
    }

    // ---- single block reduction ----
    red[tid] = term; __syncthreads();
    for (int s = 128; s > 0; s >>= 1) { if (tid < s) red[tid] += red[tid + s]; __syncthreads(); }
    if (tid == 0) ws[blockIdx.x] = make_float2(red[0], yb == 0 ? snv : 0.0f);
}

// Final reduce: exactly 256 float4 loads; loss = sum / max(n_valid, 1)
__global__ __launch_bounds__(256) void k_final(const float2* __restrict__ ws,
                                               float* __restrict__ out)
{
    const int tid = threadIdx.x;
    const float4* w4 = (const float4*)ws;          // NBLK/2 = 256 float4
    float4 v = w4[tid];
    __shared__ float red[256];
    red[tid] = v.x + v.z; __syncthreads();
    for (int st = 128; st > 0; st >>= 1) { if (tid < st) red[tid] += red[tid + st]; __syncthreads(); }
    float S = red[0]; __syncthreads();
    red[tid] = v.y + v.w; __syncthreads();
    for (int st = 128; st > 0; st >>= 1) { if (tid < st) red[tid] += red[tid + st]; __syncthreads(); }
    if (tid == 0) out[0] = S / fmaxf(red[0], 1.0f);
}

extern "C" void kernel_launch(void* const* d_in, const int* in_sizes, int n_in,
                              void* d_out, int out_size, void* d_ws, size_t ws_size,
                              hipStream_t stream)
{
    const float* in = (const float*)d_in[0];
    const float* tgt = (const float*)d_in[1];
    float2* ws = (float2*)d_ws;

    k_main<<<NBLK, 256, 0, stream>>>(in, tgt, ws);
    k_final<<<1, 256, 0, stream>>>(ws, (float*)d_out);
}

// Round 7
// 21.329 us; speedup vs baseline: 1.5730x; 1.5730x over previous
//
#include <hip/hip_runtime.h>
#include <math.h>

// Problem constants (match reference setup_inputs)
#define BS 32
#define NA 3
#define NC 80
#define HH 52
#define WW 52
#define TPER 50                 // targets per batch image
#define NTT (BS * TPER)         // 1600 total targets
#define HW (HH * WW)            // 2704
#define CPB (NA * HW)           // 8112 cells per batch image
#define CH (5 + NC)             // 85 channels per anchor
#define CELLS_PER_BLK 1024      // 256 threads x 4 cells each
#define CBPB 8                  // cell-blocks per batch: 8*1024 >= 8112
#define NCELLBLK (BS * CBPB)    // 256 cells-role blocks
#define NBLK (NCELLBLK + NTT)   // 1856 blocks total (even)

__device__ __forceinline__ float sigm(float v) { return 1.0f / (1.0f + expf(-v)); }

__device__ __forceinline__ float wave_red(float t) {
    #pragma unroll
    for (int off = 32; off > 0; off >>= 1) t += __shfl_down(t, off);  // width 64
    return t;
}

// ws layout: float2 ws[NBLK] = {pre-weighted loss partial, valid-target flag}
// cells blocks: flag 0; obj block i: flag = valid(target i)

__global__ __launch_bounds__(256) void k_main(const float* __restrict__ in,
                                              const float* __restrict__ tgt,
                                              float2* __restrict__ ws)
{
    __shared__ float4 sbox[TPER];                 // {x1, x2, y1, y2}
    __shared__ int scell[TPER], scls[TPER];
    __shared__ unsigned sbm[CELLS_PER_BLK / 32];  // target-cell bitmap (cells role)
    __shared__ float wred[4];
    const int tid = threadIdx.x;
    const float aw[3] = {1.25f, 2.0f, 4.125f};
    const float ah[3] = {1.625f, 3.75f, 2.875f};

    if (blockIdx.x < NCELLBLK) {
        // ---------------- cells role: noobj BCE + a_loss, 4 cells/thread ----------------
        const int b  = blockIdx.x >> 3;           // / CBPB
        const int lo = (blockIdx.x & 7) * CELLS_PER_BLK;
        if (tid < CELLS_PER_BLK / 32) sbm[tid] = 0u;
        int mycell = -1;
        if (tid < TPER) {
            const float* p = tgt + (size_t)(b * TPER + tid) * 5;
            float c0 = p[0], c1 = p[1], c2 = p[2], c3 = p[3], c4 = p[4];
            bool valid = (c0 + c1 + c2 + c3 + c4) > 0.0f;
            float gx = c1 * WW, gy = c2 * HH, gw = c3 * WW, gh = c4 * HH;
            int gi = (int)gx; gi = gi < 0 ? 0 : (gi > WW - 1 ? WW - 1 : gi);
            int gj = (int)gy; gj = gj < 0 ? 0 : (gj > HH - 1 ? HH - 1 : gj);
            int bn = 0; float best = -1.0f;
            for (int a = 0; a < 3; ++a) {
                float inter = fminf(gw, aw[a]) * fminf(gh, ah[a]);
                float uni = gw * gh + aw[a] * ah[a] - inter;
                float iou = inter / (uni + 1e-16f);
                if (iou > best) { best = iou; bn = a; }   // strict >: argmax keeps first
            }
            if (valid) {
                sbox[tid] = make_float4(gx - 0.5f * gw, gx + 0.5f * gw,
                                        gy - 0.5f * gh, gy + 0.5f * gh);
                mycell = bn * HW + gj * WW + gi;
            } else {
                sbox[tid] = make_float4(1e30f, 1e30f, 1e30f, 1e30f);  // inert sentinel
            }
        }
        __syncthreads();
        if (mycell >= lo && mycell < lo + CELLS_PER_BLK)
            atomicOr(&sbm[(mycell - lo) >> 5], 1u << ((mycell - lo) & 31));
        __syncthreads();

        const int idx0 = lo + tid;
        float term = 0.0f;
        float P1[4], P2[4], Q1[4], Q2[4], A2[4], CF[4];
        bool ACT[4], IGN[4] = {false, false, false, false};
        #pragma unroll
        for (int k = 0; k < 4; ++k) {
            int idx = idx0 + k * 256;
            ACT[k] = idx < CPB;
            P1[k] = 0.0f; P2[k] = 0.0f; Q1[k] = 0.0f; Q2[k] = 0.0f;
            A2[k] = 1e30f; CF[k] = 0.5f;
            if (ACT[k]) {
                int a = idx / HW;
                int r = idx - a * HW;
                int yy = r / WW;
                int xx = r - yy * WW;
                const float* base = in + ((size_t)b * (NA * CH) + a * CH) * HW + r;
                float xr = base[0], yr = base[HW], wr = base[2 * HW],
                      hr = base[3 * HW], cr = base[4 * HW];
                float sx = sigm(xr), sy = sigm(yr);
                CF[k] = sigm(cr);
                float px = sx + (float)xx, py = sy + (float)yy;
                float pw = expf(wr) * aw[a], ph = expf(hr) * ah[a];
                P1[k] = px - 0.5f * pw; P2[k] = px + 0.5f * pw;
                Q1[k] = py - 0.5f * ph; Q2[k] = py + 0.5f * ph;
                A2[k] = pw * ph + 1e-16f;
                term += 0.05f * ((sx - 0.5f) * (sx - 0.5f) + (sy - 0.5f) * (sy - 0.5f)
                                 + wr * wr + hr * hr);        // 0.1/2 pre-weight
            }
        }
        for (int t = 0; t < TPER; ++t) {
            float4 bx = sbox[t];                              // one ds_read_b128 / target
            float ar = (bx.y - bx.x) * (bx.w - bx.z);         // area1 (0 for sentinel)
            #pragma unroll
            for (int k = 0; k < 4; ++k) {
                float iw = fmaxf(fminf(bx.y, P2[k]) - fmaxf(bx.x, P1[k]), 0.0f);
                float ih = fmaxf(fminf(bx.w, Q2[k]) - fmaxf(bx.z, Q1[k]), 0.0f);
                float inter = iw * ih;
                // iou >= 0.5  <=>  3*inter >= area1 + area2 + eps (denominator > 0)
                IGN[k] = IGN[k] || (3.0f * inter >= ar + A2[k]);
            }
        }
        #pragma unroll
        for (int k = 0; k < 4; ++k) {
            int d = tid + k * 256;
            bool ist = (sbm[d >> 5] >> (d & 31)) & 1u;
            if (ACT[k] && !IGN[k] && !ist)
                term += -logf(fmaxf(1.0f - CF[k], 1e-12f));   // noobj pre-weight 5*0.2=1
        }
        term = wave_red(term);
        if ((tid & 63) == 0) wred[tid >> 6] = term;
        __syncthreads();
        if (tid == 0)
            ws[blockIdx.x] = make_float2(wred[0] + wred[1] + wred[2] + wred[3], 0.0f);
    } else {
        // ---------------- obj role: one target per block ----------------
        const int i = blockIdx.x - NCELLBLK;       // global target index
        const int b = i / TPER;
        const int t = i - b * TPER;
        if (tid < TPER) {
            const float* p = tgt + (size_t)(b * TPER + tid) * 5;
            float c0 = p[0], c1 = p[1], c2 = p[2], c3 = p[3], c4 = p[4];
            bool valid = (c0 + c1 + c2 + c3 + c4) > 0.0f;
            float gx = c1 * WW, gy = c2 * HH, gw = c3 * WW, gh = c4 * HH;
            int gi = (int)gx; gi = gi < 0 ? 0 : (gi > WW - 1 ? WW - 1 : gi);
            int gj = (int)gy; gj = gj < 0 ? 0 : (gj > HH - 1 ? HH - 1 : gj);
            int bn = 0; float best = -1.0f;
            for (int a = 0; a < 3; ++a) {
                float inter = fminf(gw, aw[a]) * fminf(gh, ah[a]);
                float uni = gw * gh + aw[a] * ah[a] - inter;
                float iou = inter / (uni + 1e-16f);
                if (iou > best) { best = iou; bn = a; }
            }
            scell[tid] = valid ? (bn * HW + gj * WW + gi) : -1;
            int cls = (int)c0; cls = cls < 0 ? 0 : (cls > NC - 1 ? NC - 1 : cls);
            scls[tid] = cls;
        }
        __syncthreads();
        const int cell = scell[t];                 // broadcast via LDS
        int a = 0, r = 0;
        float v = 0.0f;
        if (cell >= 0) {                           // issue scattered loads EARLY
            a = cell / HW;
            r = cell - a * HW;
            const float* bp = in + ((size_t)b * (NA * CH) + a * CH) * HW + r;
            if (tid < 85) v = bp[(size_t)tid * HW];   // channel == tid
        }
        const int lane = tid & 63;                 // same pattern in every wave
        bool m = (lane < TPER) && (cell >= 0) && (scell[lane] == cell);
        unsigned long long mask = __ballot(m);     // matching valid targets
        bool owner = (cell >= 0) && ((mask >> (t + 1)) == 0ULL);  // no later writer
        if (!owner) {                              // uniform across block — safe
            if (tid == 0) ws[blockIdx.x] = make_float2(0.0f, cell >= 0 ? 1.0f : 0.0f);
            return;
        }
        float term = 0.0f;                         // mask logic overlaps load latency
        if (tid < 5) {
            const float* p = tgt + (size_t)i * 5;
            if (tid == 0) {
                float gx = p[1] * WW; int gi = r - (r / WW) * WW;
                float d = sigm(v) - (gx - (float)gi); term = 0.5f * d * d;
            } else if (tid == 1) {
                float gy = p[2] * HH; int gj = r / WW;
                float d = sigm(v) - (gy - (float)gj); term = 0.5f * d * d;
            } else if (tid == 2) {
                float d = v - logf(p[3] * WW / aw[a] + 1e-16f); term = 0.5f * d * d;
            } else if (tid == 3) {
                float d = v - logf(p[4] * HH / ah[a] + 1e-16f); term = 0.5f * d * d;
            } else {
                term = -5.0f * logf(fmaxf(sigm(v), 1e-12f));
            }
        } else if (tid < 85) {
            int c = tid - 5;
            bool pos = false;                      // multi-hot union over colliding targets
            unsigned long long mm = mask;
            while (mm) { int t2 = __ffsll(mm) - 1; mm &= mm - 1; pos = pos || (scls[t2] == c); }
            float p = sigm(v);
            term = pos ? -logf(fmaxf(p, 1e-12f)) : -logf(fmaxf(1.0f - p, 1e-12f));
        }
        term = wave_red(term);
        if ((tid & 63) == 0) wred[tid >> 6] = term;
        __syncthreads();
        if (tid == 0)
            ws[blockIdx.x] = make_float2(wred[0] + wred[1] + wred[2] + wred[3], 1.0f);
    }
}

// Final reduce: 928 float4 loads; loss = sum(partials) / max(n_valid, 1)
__global__ __launch_bounds__(256) void k_final(const float2* __restrict__ ws,
                                               float* __restrict__ out)
{
    const int tid = threadIdx.x;
    const float4* w4 = (const float4*)ws;          // NBLK/2 = 928 float4
    float s = 0.0f, nv = 0.0f;
    for (int i = tid; i < NBLK / 2; i += 256) {
        float4 v = w4[i];
        s += v.x + v.z;
        nv += v.y + v.w;
    }
    __shared__ float wr0[4], wr1[4];
    s = wave_red(s);
    nv = wave_red(nv);
    if ((tid & 63) == 0) { wr0[tid >> 6] = s; wr1[tid >> 6] = nv; }
    __syncthreads();
    if (tid == 0) {
        float S = wr0[0] + wr0[1] + wr0[2] + wr0[3];
        float N = wr1[0] + wr1[1] + wr1[2] + wr1[3];
        out[0] = S / fmaxf(N, 1.0f);
    }
}

extern "C" void kernel_launch(void* const* d_in, const int* in_sizes, int n_in,
                              void* d_out, int out_size, void* d_ws, size_t ws_size,
                              hipStream_t stream)
{
    const float* in = (const float*)d_in[0];
    const float* tgt = (const float*)d_in[1];
    float2* ws = (float2*)d_ws;

    k_main<<<NBLK, 256, 0, stream>>>(in, tgt, ws);
    k_final<<<1, 256, 0, stream>>>(ws, (float*)d_out);
}